// Round 8
// baseline (5784.532 us; speedup 1.0000x reference)
//
#include <hip/hip_runtime.h>
#include <hip/hip_bf16.h>
#include <math.h>

#define SEQL 70
#define NTOK 33278
#define ODE_STEPS 8
#define NBLK 242
#define CZ4 404

typedef __attribute__((ext_vector_type(4))) float f32x4;
typedef __attribute__((ext_vector_type(8))) short s16x8;
typedef unsigned short u16;

__device__ __forceinline__ u16 f2b(float f) {
    union { float f; unsigned int u; } a; a.f = f;
    unsigned int u = a.u;
    return (u16)((u + 0x7FFFu + ((u >> 16) & 1u)) >> 16);
}
__device__ __forceinline__ float b2f(u16 s) {
    union { unsigned int u; float f; } a; a.u = ((unsigned int)s) << 16;
    return a.f;
}

// CNF zi swizzle: row is 832 B = 6.5 x 128B groups; tail [768,832) swizzles bits 4-5 only.
__device__ __forceinline__ unsigned czoff(int row, int colb) {
    unsigned s = ((colb < 768 ? (row & 7) : (row & 3)) << 4);
    return (unsigned)(row * 832 + (colb ^ (int)s));
}

// ---------- prep kernels ----------
__global__ void cvt_pad_k(const float* __restrict__ src, u16* __restrict__ dst,
                          int G, int Nin, int Nop, int Kin, int Kp, int rs, int co) {
    size_t total = (size_t)G * Nop * Kp;
    for (size_t idx = (size_t)blockIdx.x * 256 + threadIdx.x; idx < total;
         idx += (size_t)gridDim.x * 256) {
        int k = (int)(idx % Kp);
        size_t t2 = idx / Kp;
        int j = (int)(t2 % Nop);
        int g = (int)(t2 / Nop);
        float v = 0.f;
        if (j < Nin && k < Kin) v = src[((size_t)g * Nin + j) * rs + co + k];
        dst[idx] = f2b(v);
    }
}

__global__ void bias_k(const float* __restrict__ bih, const float* __restrict__ bhh,
                       float* __restrict__ o, int Nin, int Nop) {
    int idx = blockIdx.x * 256 + threadIdx.x;
    if (idx >= 4 * Nop) return;
    int g = idx / Nop, j = idx % Nop;
    o[idx] = (j < Nin) ? (bih[g * Nin + j] + bhh[g * Nin + j]) : 0.f;
}

__global__ void wtdwx_k(const float* __restrict__ cw, float* __restrict__ wt,
                        float* __restrict__ dwx) {
    int i = blockIdx.x * 256 + threadIdx.x;
    if (i < 400) {
        wt[i]  = cw[(size_t)i * 401];
        dwx[i] = cw[(size_t)i * 401 + 1 + i];
    }
}

__global__ void h0cvt_k(const float* __restrict__ h0, u16* __restrict__ hb, int N, int Kp) {
    int idx = blockIdx.x * 256 + threadIdx.x;
    if (idx >= 16 * Kp) return;
    int b = idx / Kp, k = idx % Kp;
    hb[idx] = f2b(k < N ? h0[b * N + k] : 0.f);
}

__global__ void embed_k(const int* __restrict__ tok, const float* __restrict__ emb,
                        u16* __restrict__ x0) {
    int idx = blockIdx.x * 256 + threadIdx.x;
    if (idx >= 1152 * 416) return;
    int r = idx / 416, k = idx - r * 416;
    float v = 0.f;
    if (r < SEQL * 16 && k < 400) v = emb[(size_t)tok[r] * 400 + k];
    x0[idx] = f2b(v);
}

__global__ void rowsumsq_k(const float* __restrict__ X, float* __restrict__ o, int K) {
    int r = blockIdx.x;
    const float* xr = X + (size_t)r * K;
    int lane = threadIdx.x;
    float s = 0.f;
    for (int k = lane; k < K; k += 64) { float v = xr[k]; s += v * v; }
#pragma unroll
    for (int off = 1; off < 64; off <<= 1) s += __shfl_xor(s, off, 64);
    if (lane == 0) o[r] = s;
}

__global__ void ucomb_k(const float* __restrict__ e2, const float* __restrict__ dl,
                        float* __restrict__ u) {
    int i = blockIdx.x * 256 + threadIdx.x;
    if (i < NTOK) u[i] = -0.5f * e2[i] - dl[i];
}

// ---------- GEMM: C[M,N](fp32) = A[M,Kp](bf16) * B[N,Kp]^T(bf16) (+ u[n]) ----------
__global__ void gemm_bt_k(const u16* __restrict__ A, const u16* __restrict__ B,
                          float* __restrict__ C, int Kp, int lda, int ldb, int ldc,
                          int Mreal, int Nreal, const float* __restrict__ uvec) {
    const int tid = threadIdx.x;
    const int wid = tid >> 6, lane = tid & 63;
    const int la = lane & 15, lk = (lane >> 4) * 8;
    const int m0 = blockIdx.y * 64 + wid * 16;
    const int n0 = blockIdx.x * 64;
    const f32x4 Z4 = {0.f, 0.f, 0.f, 0.f};
    f32x4 acc[4] = {Z4, Z4, Z4, Z4};
    const u16* Ar = A + (size_t)(m0 + la) * lda + lk;
    const u16* Br = B + (size_t)(n0 + la) * ldb + lk;
    for (int k = 0; k < Kp; k += 32) {
        s16x8 a = *(const s16x8*)(Ar + k);
#pragma unroll
        for (int nt = 0; nt < 4; ++nt) {
            s16x8 b = *(const s16x8*)(Br + (size_t)nt * 16 * ldb + k);
            acc[nt] = __builtin_amdgcn_mfma_f32_16x16x32_bf16(a, b, acc[nt], 0, 0, 0);
        }
    }
    const int mr = m0 + (lane >> 4) * 4;
#pragma unroll
    for (int nt = 0; nt < 4; ++nt) {
        int cc = n0 + nt * 16 + la;
        if (cc >= Nreal) continue;
        float uv = uvec ? uvec[cc] : 0.f;
#pragma unroll
        for (int r = 0; r < 4; ++r) {
            int rr = mr + r;
            if (rr < Mreal) C[(size_t)rr * ldc + cc] = acc[nt][r] + uv;
        }
    }
}

// ---------- per-role tree barrier + cross-role generation wait ----------
// Spin RELAXED (no invalidate storm); one ACQUIRE pulls cross-XCD data after exit.
__device__ __forceinline__ void rolebar(int* base, int nb, int ngrp, int roleBlk, int iter) {
    __syncthreads();
    if (threadIdx.x == 0) {
        int grp = roleBlk % ngrp;
        int gsz = nb / ngrp + ((grp < (nb % ngrp)) ? 1 : 0);
        int* gc   = base + grp * 16;
        int* root = base + ngrp * 16;
        int* gen  = base + ngrp * 16 + 16;
        int old = __hip_atomic_fetch_add(gc, 1, __ATOMIC_ACQ_REL, __HIP_MEMORY_SCOPE_AGENT);
        if ((old % gsz) == gsz - 1) {
            int r = __hip_atomic_fetch_add(root, 1, __ATOMIC_ACQ_REL, __HIP_MEMORY_SCOPE_AGENT);
            if ((r % ngrp) == ngrp - 1)
                __hip_atomic_fetch_add(gen, 1, __ATOMIC_ACQ_REL, __HIP_MEMORY_SCOPE_AGENT);
        }
        while (__hip_atomic_load(gen, __ATOMIC_RELAXED, __HIP_MEMORY_SCOPE_AGENT) <= iter)
            __builtin_amdgcn_s_sleep(4);
        (void)__hip_atomic_load(gen, __ATOMIC_ACQUIRE, __HIP_MEMORY_SCOPE_AGENT);
    }
    __syncthreads();
}
__device__ __forceinline__ void waitgen(int* gen, int needed) {
    if (threadIdx.x == 0) {
        while (__hip_atomic_load(gen, __ATOMIC_RELAXED, __HIP_MEMORY_SCOPE_AGENT) < needed)
            __builtin_amdgcn_s_sleep(4);
        (void)__hip_atomic_load(gen, __ATOMIC_ACQUIRE, __HIP_MEMORY_SCOPE_AGENT);
    }
    __syncthreads();
}

// ---------- persistent-weight 3-layer LSTM, decoupled role pipelines ----------
__global__ __launch_bounds__(768, 3) void lstm_k(
    const float* __restrict__ c00, const float* __restrict__ c01,
    const float* __restrict__ c02,
    const u16* __restrict__ Whh0p, const u16* __restrict__ Wih1p,
    const u16* __restrict__ Whh1p, const u16* __restrict__ Wih2p,
    const u16* __restrict__ Whh2p,
    const float* __restrict__ xW0, const float* __restrict__ bias2v,
    const float* __restrict__ bias1v,
    u16* __restrict__ ys0s, u16* __restrict__ ys1s, u16* __restrict__ ys2s,
    float* __restrict__ oh1, float* __restrict__ oc1,
    float* __restrict__ oh2, float* __restrict__ oc2,
    float* __restrict__ oh3, float* __restrict__ oc3,
    int* __restrict__ bar)
{
    __shared__ __align__(16) char smem[162816];
    u16* wlds = (u16*)smem;                 // 147456 B frag slots
    float* gl = (float*)(smem + 147456);    // [12 waves][16 la][20] f32
    const int tid = threadIdx.x;
    const int bid = blockIdx.x;
    const int wv = tid >> 6, lane = tid & 63;
    const int la = lane & 15, lg = lane >> 4;

    int role, jb;
    if (bid < 72) { role = 0; jb = bid; }
    else if (bid < 216) { role = 1; jb = bid - 72; }
    else { role = 2; jb = bid - 216; }

    int* bar0 = bar;          // 8 groups: gc[0..127], root@128, gen@144
    int* bar1 = bar + 256;    // 16 groups: gc[0..255], root@256, gen@272
    int* bar2 = bar + 768;    // 1 group: gc@0, root@16, gen@32
    int* g0 = bar0 + 144;
    int* g1 = bar1 + 272;

    // ---- one-time weight preload (roles 0,1) ----
    if (role == 0) {
        for (int s = tid; s < 4 * 36 * 64; s += 768) {
            int ln = s & 63, kt = (s >> 6) % 36, nt = s / (36 * 64);
            int row = nt * 1152 + jb * 16 + (ln & 15);
            int col = kt * 32 + (ln >> 4) * 8;
            *(s16x8*)(wlds + (size_t)s * 8) =
                *(const s16x8*)(Whh0p + (size_t)row * 1152 + col);
        }
    } else if (role == 1) {
        for (int s = tid; s < 2 * 72 * 64; s += 768) {
            int ln = s & 63, kt = (s >> 6) % 72, nt = s / (72 * 64);
            int lr = nt * 16 + (ln & 15);
            int row = (lr >> 3) * 1152 + jb * 8 + (lr & 7);
            int col8 = (ln >> 4) * 8;
            const u16* src = (kt < 36)
                ? Wih1p + (size_t)row * 1152 + kt * 32 + col8
                : Whh1p + (size_t)row * 1152 + (kt - 36) * 32 + col8;
            *(s16x8*)(wlds + (size_t)s * 8) = *(const s16x8*)src;
        }
    }
    __syncthreads();

    float c_reg = 0.f;
    for (int t = 0; t < SEQL; ++t) {
        if (role == 1) waitgen(g0, t + 1);       // ys0s slot t+1 ready
        else if (role == 2) waitgen(g1, t + 1);  // ys1s slot t+1 ready

        f32x4 acc = {0.f, 0.f, 0.f, 0.f};
        if (role == 0) {
            int nt = wv / 3, kg = wv - nt * 3;
            const u16* ar = ys0s + ((size_t)t * 16 + la) * 1152 + lg * 8;
            for (int kt = kg * 12; kt < kg * 12 + 12; ++kt) {
                s16x8 a = *(const s16x8*)(ar + kt * 32);
                s16x8 b = *(const s16x8*)(wlds + ((size_t)(nt * 36 + kt) * 64 + lane) * 8);
                acc = __builtin_amdgcn_mfma_f32_16x16x32_bf16(a, b, acc, 0, 0, 0);
            }
            *(f32x4*)(gl + wv * 320 + la * 20 + lg * 4) = acc;
        } else if (role == 1) {
            int nt = wv / 6, kg = wv - nt * 6;
            const u16* ax = ys0s + ((size_t)(t + 1) * 16 + la) * 1152 + lg * 8;
            const u16* ah = ys1s + ((size_t)t * 16 + la) * 1152 + lg * 8;
            for (int kt = kg * 12; kt < kg * 12 + 12; ++kt) {
                s16x8 a = (kt < 36) ? *(const s16x8*)(ax + kt * 32)
                                    : *(const s16x8*)(ah + (kt - 36) * 32);
                s16x8 b = *(const s16x8*)(wlds + ((size_t)(nt * 72 + kt) * 64 + lane) * 8);
                acc = __builtin_amdgcn_mfma_f32_16x16x32_bf16(a, b, acc, 0, 0, 0);
            }
            *(f32x4*)(gl + wv * 320 + la * 20 + lg * 4) = acc;
        } else {
            int nt = wv / 3, kg = wv - nt * 3;
            int k0 = (kg * 49) / 3, k1 = ((kg + 1) * 49) / 3;
            const u16* ax = ys1s + ((size_t)(t + 1) * 16 + la) * 1152 + lg * 8;
            const u16* ah = ys2s + ((size_t)t * 16 + la) * 416 + lg * 8;
            int wr = nt * 416 + jb * 16 + la;
            for (int kt = k0; kt < k1; ++kt) {
                s16x8 a, b;
                if (kt < 36) {
                    a = *(const s16x8*)(ax + kt * 32);
                    b = *(const s16x8*)(Wih2p + (size_t)wr * 1152 + kt * 32 + lg * 8);
                } else {
                    a = *(const s16x8*)(ah + (kt - 36) * 32);
                    b = *(const s16x8*)(Whh2p + (size_t)wr * 416 + (kt - 36) * 32 + lg * 8);
                }
                acc = __builtin_amdgcn_mfma_f32_16x16x32_bf16(a, b, acc, 0, 0, 0);
            }
            *(f32x4*)(gl + wv * 320 + la * 20 + lg * 4) = acc;
        }
        __syncthreads();
        // ---- activation ----
        if (role == 1) {
            if (tid < 128) {
                int u = tid & 7, tb = tid >> 3;
                int ug = jb * 8 + u;
                float gv[4];
#pragma unroll
                for (int g = 0; g < 4; ++g) {
                    int lr = g * 8 + u;
                    int nt = lr >> 4, li = lr & 15;
                    float s = 0.f;
#pragma unroll
                    for (int kg = 0; kg < 6; ++kg)
                        s += gl[(nt * 6 + kg) * 320 + li * 20 + tb];
                    gv[g] = s + bias1v[g * 1152 + ug];
                }
                float cprev = (t == 0) ? ((ug < 1150) ? c01[tb * 1150 + ug] : 0.f) : c_reg;
                float si = 1.f / (1.f + expf(-gv[0]));
                float sf = 1.f / (1.f + expf(-gv[1]));
                float so = 1.f / (1.f + expf(-gv[3]));
                float cn = sf * cprev + si * tanhf(gv[2]);
                float hn = so * tanhf(cn);
                c_reg = cn;
                if (ug < 1150) {
                    ys1s[((size_t)(t + 1) * 16 + tb) * 1152 + ug] = f2b(hn);
                    if (t == SEQL - 1) { oh2[tb * 1150 + ug] = hn; oc2[tb * 1150 + ug] = cn; }
                }
            }
        } else if (tid < 256) {
            int u = tid & 15, tb = tid >> 4;
            int ug = jb * 16 + u;
            float gv[4];
#pragma unroll
            for (int g = 0; g < 4; ++g) {
                float s = 0.f;
#pragma unroll
                for (int kg = 0; kg < 3; ++kg)
                    s += gl[(g * 3 + kg) * 320 + u * 20 + tb];
                gv[g] = s + ((role == 0)
                             ? xW0[((size_t)t * 16 + tb) * 4608 + g * 1152 + ug]
                             : bias2v[g * 416 + ug]);
            }
            int N = (role == 0) ? 1150 : 400;
            const float* c0i = (role == 0) ? c00 : c02;
            float cprev = (t == 0) ? ((ug < N) ? c0i[tb * N + ug] : 0.f) : c_reg;
            float si = 1.f / (1.f + expf(-gv[0]));
            float sf = 1.f / (1.f + expf(-gv[1]));
            float so = 1.f / (1.f + expf(-gv[3]));
            float cn = sf * cprev + si * tanhf(gv[2]);
            float hn = so * tanhf(cn);
            c_reg = cn;
            if (ug < N) {
                if (role == 0) {
                    ys0s[((size_t)(t + 1) * 16 + tb) * 1152 + ug] = f2b(hn);
                    if (t == SEQL - 1) { oh1[tb * 1150 + ug] = hn; oc1[tb * 1150 + ug] = cn; }
                } else {
                    ys2s[((size_t)(t + 1) * 16 + tb) * 416 + ug] = f2b(hn);
                    if (t == SEQL - 1) { oh3[tb * 400 + ug] = hn; oc3[tb * 400 + ug] = cn; }
                }
            }
        }
        if (role == 0) rolebar(bar0, 72, 8, jb, t);
        else if (role == 1) rolebar(bar1, 144, 16, jb, t);
        else rolebar(bar2, 26, 1, jb, t);
    }
}

// ---------- fused CNF: transposed MFMA, 12 waves (round-5-proven structure) ----------
__global__ __launch_bounds__(768, 3) void cnf_k(const float* __restrict__ emb,
                                                const u16* __restrict__ Wxp,
                                                const float* __restrict__ wtv,
                                                const float* __restrict__ bvv,
                                                const float* __restrict__ dwxv,
                                                float* __restrict__ dl) {
    __shared__ __align__(16) char smem[159744];
    float* z0s = (float*)smem;                              // [64][CZ4] f32 master
    char*  zib = smem + 64 * CZ4 * 4;                       // [64][832B] bf16 eval
    float* dsc = (float*)(smem + 64 * CZ4 * 4 + 64 * 832);  // [12][64]
    const int tid = threadIdx.x;
    const int m0 = blockIdx.x * 64;
    const int wv = tid >> 6, lane = tid & 63;
    const int la = lane & 15, lg = lane >> 4;

    for (int idx = tid; idx < 64 * 416; idx += 768) {
        int r = idx / 416, cc = idx - r * 416;
        int row = m0 + r;
        float v = (cc < 400 && row < NTOK) ? emb[(size_t)row * 400 + cc] : 0.f;
        if (cc < 400) z0s[r * CZ4 + cc] = v;
        *(u16*)(zib + czoff(r, cc * 2)) = f2b(v);
    }

    const int Qw = (wv == 0) ? 3 : 2;
    const int ntb = (wv == 0) ? 0 : 3 + 2 * (wv - 1);
    const f32x4 Z4 = {0.f, 0.f, 0.f, 0.f};
    f32x4 wt4[3], bv4[3], dw4[3];
#pragma unroll
    for (int q = 0; q < 3; ++q) {
        wt4[q] = Z4; bv4[q] = Z4; dw4[q] = Z4;
        if (q < Qw) {
            int c4 = (ntb + q) * 16 + lg * 4;
            wt4[q] = *(const f32x4*)(wtv + c4);
            bv4[q] = *(const f32x4*)(bvv + c4);
            dw4[q] = *(const f32x4*)(dwxv + c4);
        }
    }
    __syncthreads();

    const float dt = 1.f / ODE_STEPS, dt6 = dt / 6.f;
    f32x4 Aacc[4][3];
#pragma unroll
    for (int m = 0; m < 4; ++m)
#pragma unroll
        for (int q = 0; q < 3; ++q) Aacc[m][q] = Z4;
    float divacc[4] = {0.f, 0.f, 0.f, 0.f};

#pragma unroll 1
    for (int st = 0; st < ODE_STEPS; ++st) {
        float t0 = st * dt;
#pragma unroll 1
        for (int s = 0; s < 4; ++s) {
            float ts = t0 + ((s == 0) ? 0.f : (s == 3) ? dt : 0.5f * dt);
            float wgt = (s == 1 || s == 2) ? 2.f : 1.f;
            float cs = (s == 2) ? dt : 0.5f * dt;
            f32x4 pre[4][3];
#pragma unroll
            for (int m = 0; m < 4; ++m)
#pragma unroll
                for (int q = 0; q < 3; ++q) pre[m][q] = Z4;
            for (int kk = 0; kk < 13; ++kk) {
                s16x8 aW[3];
#pragma unroll
                for (int q = 0; q < 3; ++q)
                    if (q < Qw)
                        aW[q] = *(const s16x8*)(Wxp + (size_t)((ntb + q) * 16 + la) * 416 +
                                                kk * 32 + lg * 8);
#pragma unroll
                for (int m = 0; m < 4; ++m) {
                    int rr = m * 16 + la;
                    s16x8 bz = *(const s16x8*)(zib + czoff(rr, (kk * 32 + lg * 8) * 2));
#pragma unroll
                    for (int q = 0; q < 3; ++q)
                        if (q < Qw)
                            pre[m][q] = __builtin_amdgcn_mfma_f32_16x16x32_bf16(
                                aW[q], bz, pre[m][q], 0, 0, 0);
                }
            }
            __syncthreads();
            f32x4 tb4[3], dwg[3];
#pragma unroll
            for (int q = 0; q < 3; ++q)
                if (q < Qw) { tb4[q] = ts * wt4[q] + bv4[q]; dwg[q] = wgt * dw4[q]; }
#pragma unroll
            for (int m = 0; m < 4; ++m) {
                int row = m * 16 + la;
#pragma unroll
                for (int q = 0; q < 3; ++q) {
                    if (q >= Qw) continue;
                    int c4 = (ntb + q) * 16 + lg * 4;
                    f32x4 z04 = *(const f32x4*)(z0s + row * CZ4 + c4);
                    f32x4 ev;
#pragma unroll
                    for (int r = 0; r < 4; ++r) {
                        float pv = pre[m][q][r] + tb4[q][r];
                        float kz = fmaxf(pv, 0.f);
                        if (pv > 0.f) divacc[m] += dwg[q][r];
                        if (s < 3) {
                            Aacc[m][q][r] += wgt * kz;
                            ev[r] = z04[r] + cs * kz;
                        } else {
                            float zn = z04[r] + dt6 * (Aacc[m][q][r] + kz);
                            ev[r] = zn; z04[r] = zn; Aacc[m][q][r] = 0.f;
                        }
                    }
                    if (s == 3) *(f32x4*)(z0s + row * CZ4 + c4) = z04;
                    ushort4 pk;
                    pk.x = f2b(ev[0]); pk.y = f2b(ev[1]);
                    pk.z = f2b(ev[2]); pk.w = f2b(ev[3]);
                    *(ushort4*)(zib + czoff(row, c4 * 2)) = pk;
                }
            }
            __syncthreads();
        }
    }
#pragma unroll
    for (int m = 0; m < 4; ++m) {
        float v = divacc[m];
        v += __shfl_xor(v, 16, 64);
        v += __shfl_xor(v, 32, 64);
        if (lane < 16) dsc[wv * 64 + m * 16 + la] = v;
    }
    __syncthreads();
    for (int row = tid; row < 64; row += 768) {
        float s = 0.f;
#pragma unroll
        for (int w = 0; w < 12; ++w) s += dsc[w * 64 + row];
        if (m0 + row < NTOK) dl[m0 + row] = -dt6 * s;
    }
}

// ---------- in-place log(softmax(x)+1e-8) per row ----------
__global__ void logsoftmax_k(float* __restrict__ L, int n) {
    const int row = blockIdx.x;
    float* R = L + (size_t)row * n;
    const int tid = threadIdx.x;
    float mx = -INFINITY, s = 0.f;
    for (int c = tid; c < n; c += 256) {
        float v = R[c];
        float nm = fmaxf(mx, v);
        s = s * expf(mx - nm) + expf(v - nm);
        mx = nm;
    }
#pragma unroll
    for (int off = 1; off < 64; off <<= 1) {
        float om = __shfl_xor(mx, off, 64);
        float os = __shfl_xor(s, off, 64);
        float nm = fmaxf(mx, om);
        s = s * expf(mx - nm) + os * expf(om - nm);
        mx = nm;
    }
    __shared__ float smx[4], ssm[4];
    if ((tid & 63) == 0) { smx[tid >> 6] = mx; ssm[tid >> 6] = s; }
    __syncthreads();
    float bm = fmaxf(fmaxf(smx[0], smx[1]), fmaxf(smx[2], smx[3]));
    float bs = ssm[0] * expf(smx[0] - bm) + ssm[1] * expf(smx[1] - bm) +
               ssm[2] * expf(smx[2] - bm) + ssm[3] * expf(smx[3] - bm);
    float lz = logf(bs);
    for (int c = tid; c < n; c += 256) {
        float v = R[c];
        R[c] = logf(expf(v - bm) + 1e-8f * bs) - lz;
    }
}

extern "C" void kernel_launch(void* const* d_in, const int* in_sizes, int n_in,
                              void* d_out, int out_size, void* d_ws, size_t ws_size,
                              hipStream_t stream) {
    const int*   tokens = (const int*)d_in[0];
    const float* h00 = (const float*)d_in[1];
    const float* c00 = (const float*)d_in[2];
    const float* h01 = (const float*)d_in[3];
    const float* c01 = (const float*)d_in[4];
    const float* h02 = (const float*)d_in[5];
    const float* c02 = (const float*)d_in[6];
    const float* embW = (const float*)d_in[7];
    const float* Wih0 = (const float*)d_in[8];
    const float* Whh0 = (const float*)d_in[9];
    const float* bih0 = (const float*)d_in[10];
    const float* bhh0 = (const float*)d_in[11];
    const float* Wih1 = (const float*)d_in[12];
    const float* Whh1 = (const float*)d_in[13];
    const float* bih1 = (const float*)d_in[14];
    const float* bhh1 = (const float*)d_in[15];
    const float* Wih2 = (const float*)d_in[16];
    const float* Whh2 = (const float*)d_in[17];
    const float* bih2 = (const float*)d_in[18];
    const float* bhh2 = (const float*)d_in[19];
    const float* cnfW = (const float*)d_in[20];
    const float* cnfb = (const float*)d_in[21];
    float* out = (float*)d_out;

    char* p = (char*)d_ws;
    auto alloc = [&](size_t bytes) -> void* {
        void* r = (void*)p;
        p += (bytes + 255) & ~(size_t)255;
        return r;
    };
    u16*   emb_p = (u16*)alloc((size_t)33280 * 416 * 2);
    u16*   x0    = (u16*)alloc((size_t)1152 * 416 * 2);
    u16*   ys0s  = (u16*)alloc((size_t)1136 * 1152 * 2);
    u16*   ys1s  = (u16*)alloc((size_t)1136 * 1152 * 2);
    u16*   ys2s  = (u16*)alloc((size_t)1184 * 416 * 2);   // +pad for gemm overread
    float* xW    = (float*)alloc((size_t)1120 * 4608 * 4);
    u16*   Wih0p = (u16*)alloc((size_t)4608 * 416 * 2);
    u16*   Whh0p = (u16*)alloc((size_t)4608 * 1152 * 2);
    u16*   Wih1p = (u16*)alloc((size_t)4608 * 1152 * 2);
    u16*   Whh1p = (u16*)alloc((size_t)4608 * 1152 * 2);
    u16*   Wih2p = (u16*)alloc((size_t)1664 * 1152 * 2);
    u16*   Whh2p = (u16*)alloc((size_t)1664 * 416 * 2);
    float* bias0 = (float*)alloc((size_t)4608 * 4);
    float* bias1 = (float*)alloc((size_t)4608 * 4);
    float* bias2 = (float*)alloc((size_t)1664 * 4);
    u16*   Wxp   = (u16*)alloc((size_t)416 * 416 * 2);
    float* wtv   = (float*)alloc((size_t)400 * 4);
    float* dwx   = (float*)alloc((size_t)400 * 4);
    float* dl    = (float*)alloc((size_t)NTOK * 4);
    float* e2    = (float*)alloc((size_t)NTOK * 4);
    float* uvec  = (float*)alloc((size_t)NTOK * 4);
    int*   bar   = (int*)alloc(4096);

    size_t OM = (size_t)SEQL * 16 * NTOK;
    float* oh1 = out + OM;
    float* oc1 = oh1 + 16 * 1150;
    float* oh2 = oc1 + 16 * 1150;
    float* oc2 = oh2 + 16 * 1150;
    float* oh3 = oc2 + 16 * 1150;
    float* oc3 = oh3 + 16 * 400;

    hipMemsetAsync(bar, 0, 4096, stream);
    hipMemsetAsync(ys0s, 0, (size_t)1136 * 1152 * 2, stream);
    hipMemsetAsync(ys1s, 0, (size_t)1136 * 1152 * 2, stream);
    hipMemsetAsync(ys2s, 0, (size_t)1184 * 416 * 2, stream);

    cvt_pad_k<<<2048, 256, 0, stream>>>(Wih0, Wih0p, 4, 1150, 1152, 400, 416, 400, 0);
    cvt_pad_k<<<2048, 256, 0, stream>>>(Whh0, Whh0p, 4, 1150, 1152, 1150, 1152, 1150, 0);
    cvt_pad_k<<<2048, 256, 0, stream>>>(Wih1, Wih1p, 4, 1150, 1152, 1150, 1152, 1150, 0);
    cvt_pad_k<<<2048, 256, 0, stream>>>(Whh1, Whh1p, 4, 1150, 1152, 1150, 1152, 1150, 0);
    cvt_pad_k<<<2048, 256, 0, stream>>>(Wih2, Wih2p, 4, 400, 416, 1150, 1152, 1150, 0);
    cvt_pad_k<<<2048, 256, 0, stream>>>(Whh2, Whh2p, 4, 400, 416, 400, 416, 400, 0);
    cvt_pad_k<<<2048, 256, 0, stream>>>(embW, emb_p, 1, 33278, 33280, 400, 416, 400, 0);
    cvt_pad_k<<<2048, 256, 0, stream>>>(cnfW, Wxp, 1, 400, 416, 400, 416, 401, 1);
    bias_k<<<(4 * 1152 + 255) / 256, 256, 0, stream>>>(bih0, bhh0, bias0, 1150, 1152);
    bias_k<<<(4 * 1152 + 255) / 256, 256, 0, stream>>>(bih1, bhh1, bias1, 1150, 1152);
    bias_k<<<(4 * 416 + 255) / 256, 256, 0, stream>>>(bih2, bhh2, bias2, 400, 416);
    wtdwx_k<<<2, 256, 0, stream>>>(cnfW, wtv, dwx);
    rowsumsq_k<<<NTOK, 64, 0, stream>>>(embW, e2, 400);

    // h0 -> ys slot 0
    h0cvt_k<<<(16 * 1152 + 255) / 256, 256, 0, stream>>>(h00, ys0s, 1150, 1152);
    h0cvt_k<<<(16 * 1152 + 255) / 256, 256, 0, stream>>>(h01, ys1s, 1150, 1152);
    h0cvt_k<<<(16 * 416 + 255) / 256, 256, 0, stream>>>(h02, ys2s, 400, 416);

    // CNF (independent)
    cnf_k<<<520, 768, 0, stream>>>(embW, Wxp, wtv, cnfb, dwx, dl);
    ucomb_k<<<(NTOK + 255) / 256, 256, 0, stream>>>(e2, dl, uvec);

    // embedding + xW0 = x0 @ Wih0^T + (bih0+bhh0)
    embed_k<<<(1152 * 416 + 255) / 256, 256, 0, stream>>>(tokens, embW, x0);
    gemm_bt_k<<<dim3(72, 18), 256, 0, stream>>>(x0, Wih0p, xW, 416, 416, 416, 4608,
                                                1120, 4608, bias0);

    // persistent-weight LSTM (3 decoupled role pipelines)
    lstm_k<<<NBLK, 768, 0, stream>>>(
        c00, c01, c02, Whh0p, Wih1p, Whh1p, Wih2p, Whh2p,
        xW, bias2, bias1, ys0s, ys1s, ys2s,
        oh1, oc1, oh2, oc2, oh3, oc3, bar);

    // logits into d_out, then in-place log-softmax
    gemm_bt_k<<<dim3(520, 18), 256, 0, stream>>>(ys2s + (size_t)16 * 416, emb_p, out,
                                                 416, 416, 416, NTOK, 1120, NTOK, uvec);
    logsoftmax_k<<<1120, 256, 0, stream>>>(out, NTOK);
}

// Round 9
// 3188.154 us; speedup vs baseline: 1.8144x; 1.8144x over previous
//
#include <hip/hip_runtime.h>
#include <hip/hip_bf16.h>
#include <math.h>

#define SEQL 70
#define NTOK 33278
#define ODE_STEPS 8
#define NBLK 242
#define CZS 418

typedef __attribute__((ext_vector_type(4))) float f32x4;
typedef __attribute__((ext_vector_type(8))) short s16x8;
typedef unsigned short u16;

__device__ __forceinline__ u16 f2b(float f) {
    union { float f; unsigned int u; } a; a.f = f;
    unsigned int u = a.u;
    return (u16)((u + 0x7FFFu + ((u >> 16) & 1u)) >> 16);
}
__device__ __forceinline__ float b2f(u16 s) {
    union { unsigned int u; float f; } a; a.u = ((unsigned int)s) << 16;
    return a.f;
}

// CNF zi swizzle: row is 832 B = 6.5 x 128B groups; tail [768,832) swizzles bits 4-5 only.
__device__ __forceinline__ unsigned czoff(int row, int colb) {
    unsigned s = ((colb < 768 ? (row & 7) : (row & 3)) << 4);
    return (unsigned)(row * 832 + (colb ^ (int)s));
}

// ---------- prep kernels ----------
__global__ void cvt_pad_k(const float* __restrict__ src, u16* __restrict__ dst,
                          int G, int Nin, int Nop, int Kin, int Kp, int rs, int co) {
    size_t total = (size_t)G * Nop * Kp;
    for (size_t idx = (size_t)blockIdx.x * 256 + threadIdx.x; idx < total;
         idx += (size_t)gridDim.x * 256) {
        int k = (int)(idx % Kp);
        size_t t2 = idx / Kp;
        int j = (int)(t2 % Nop);
        int g = (int)(t2 / Nop);
        float v = 0.f;
        if (j < Nin && k < Kin) v = src[((size_t)g * Nin + j) * rs + co + k];
        dst[idx] = f2b(v);
    }
}

__global__ void bias_k(const float* __restrict__ bih, const float* __restrict__ bhh,
                       float* __restrict__ o, int Nin, int Nop) {
    int idx = blockIdx.x * 256 + threadIdx.x;
    if (idx >= 4 * Nop) return;
    int g = idx / Nop, j = idx % Nop;
    o[idx] = (j < Nin) ? (bih[g * Nin + j] + bhh[g * Nin + j]) : 0.f;
}

__global__ void wtdwx_k(const float* __restrict__ cw, float* __restrict__ wt,
                        float* __restrict__ dwx) {
    int i = blockIdx.x * 256 + threadIdx.x;
    if (i < 400) {
        wt[i]  = cw[(size_t)i * 401];
        dwx[i] = cw[(size_t)i * 401 + 1 + i];
    }
}

__global__ void h0cvt_k(const float* __restrict__ h0, u16* __restrict__ hb, int N, int Kp) {
    int idx = blockIdx.x * 256 + threadIdx.x;
    if (idx >= 16 * Kp) return;
    int b = idx / Kp, k = idx % Kp;
    hb[idx] = f2b(k < N ? h0[b * N + k] : 0.f);
}

__global__ void embed_k(const int* __restrict__ tok, const float* __restrict__ emb,
                        u16* __restrict__ x0) {
    int idx = blockIdx.x * 256 + threadIdx.x;
    if (idx >= 1152 * 416) return;
    int r = idx / 416, k = idx - r * 416;
    float v = 0.f;
    if (r < SEQL * 16 && k < 400) v = emb[(size_t)tok[r] * 400 + k];
    x0[idx] = f2b(v);
}

__global__ void rowsumsq_k(const float* __restrict__ X, float* __restrict__ o, int K) {
    int r = blockIdx.x;
    const float* xr = X + (size_t)r * K;
    int lane = threadIdx.x;
    float s = 0.f;
    for (int k = lane; k < K; k += 64) { float v = xr[k]; s += v * v; }
#pragma unroll
    for (int off = 1; off < 64; off <<= 1) s += __shfl_xor(s, off, 64);
    if (lane == 0) o[r] = s;
}

__global__ void ucomb_k(const float* __restrict__ e2, const float* __restrict__ dl,
                        float* __restrict__ u) {
    int i = blockIdx.x * 256 + threadIdx.x;
    if (i < NTOK) u[i] = -0.5f * e2[i] - dl[i];
}

// ---------- GEMM: C[M,N](fp32) = A[M,Kp](bf16) * B[N,Kp]^T(bf16) (+ u[n]) ----------
__global__ void gemm_bt_k(const u16* __restrict__ A, const u16* __restrict__ B,
                          float* __restrict__ C, int Kp, int lda, int ldb, int ldc,
                          int Mreal, int Nreal, const float* __restrict__ uvec) {
    const int tid = threadIdx.x;
    const int wid = tid >> 6, lane = tid & 63;
    const int la = lane & 15, lk = (lane >> 4) * 8;
    const int m0 = blockIdx.y * 64 + wid * 16;
    const int n0 = blockIdx.x * 64;
    const f32x4 Z4 = {0.f, 0.f, 0.f, 0.f};
    f32x4 acc[4] = {Z4, Z4, Z4, Z4};
    const u16* Ar = A + (size_t)(m0 + la) * lda + lk;
    const u16* Br = B + (size_t)(n0 + la) * ldb + lk;
    for (int k = 0; k < Kp; k += 32) {
        s16x8 a = *(const s16x8*)(Ar + k);
#pragma unroll
        for (int nt = 0; nt < 4; ++nt) {
            s16x8 b = *(const s16x8*)(Br + (size_t)nt * 16 * ldb + k);
            acc[nt] = __builtin_amdgcn_mfma_f32_16x16x32_bf16(a, b, acc[nt], 0, 0, 0);
        }
    }
    const int mr = m0 + (lane >> 4) * 4;
#pragma unroll
    for (int nt = 0; nt < 4; ++nt) {
        int cc = n0 + nt * 16 + la;
        if (cc >= Nreal) continue;
        float uv = uvec ? uvec[cc] : 0.f;
#pragma unroll
        for (int r = 0; r < 4; ++r) {
            int rr = mr + r;
            if (rr < Mreal) C[(size_t)rr * ldc + cc] = acc[nt][r] + uv;
        }
    }
}

// ---------- per-role tree barrier + cross-role generation wait ----------
__device__ __forceinline__ void rolebar(int* base, int nb, int ngrp, int roleBlk, int iter) {
    __syncthreads();
    if (threadIdx.x == 0) {
        int grp = roleBlk % ngrp;
        int gsz = nb / ngrp + ((grp < (nb % ngrp)) ? 1 : 0);
        int* gc   = base + grp * 16;
        int* root = base + ngrp * 16;
        int* gen  = base + ngrp * 16 + 16;
        int old = __hip_atomic_fetch_add(gc, 1, __ATOMIC_ACQ_REL, __HIP_MEMORY_SCOPE_AGENT);
        if ((old % gsz) == gsz - 1) {
            int r = __hip_atomic_fetch_add(root, 1, __ATOMIC_ACQ_REL, __HIP_MEMORY_SCOPE_AGENT);
            if ((r % ngrp) == ngrp - 1)
                __hip_atomic_fetch_add(gen, 1, __ATOMIC_ACQ_REL, __HIP_MEMORY_SCOPE_AGENT);
        }
        while (__hip_atomic_load(gen, __ATOMIC_RELAXED, __HIP_MEMORY_SCOPE_AGENT) <= iter)
            __builtin_amdgcn_s_sleep(4);
        (void)__hip_atomic_load(gen, __ATOMIC_ACQUIRE, __HIP_MEMORY_SCOPE_AGENT);
    }
    __syncthreads();
}
__device__ __forceinline__ void waitgen(int* gen, int needed) {
    if (threadIdx.x == 0) {
        while (__hip_atomic_load(gen, __ATOMIC_RELAXED, __HIP_MEMORY_SCOPE_AGENT) < needed)
            __builtin_amdgcn_s_sleep(4);
        (void)__hip_atomic_load(gen, __ATOMIC_ACQUIRE, __HIP_MEMORY_SCOPE_AGENT);
    }
    __syncthreads();
}

// ---------- persistent-weight 3-layer LSTM, decoupled role pipelines ----------
__global__ __launch_bounds__(768, 3) void lstm_k(
    const float* __restrict__ c00, const float* __restrict__ c01,
    const float* __restrict__ c02,
    const u16* __restrict__ Whh0p, const u16* __restrict__ Wih1p,
    const u16* __restrict__ Whh1p, const u16* __restrict__ Wih2p,
    const u16* __restrict__ Whh2p,
    const float* __restrict__ xW0, const float* __restrict__ bias2v,
    const float* __restrict__ bias1v,
    u16* __restrict__ ys0s, u16* __restrict__ ys1s, u16* __restrict__ ys2s,
    float* __restrict__ oh1, float* __restrict__ oc1,
    float* __restrict__ oh2, float* __restrict__ oc2,
    float* __restrict__ oh3, float* __restrict__ oc3,
    int* __restrict__ bar)
{
    __shared__ __align__(16) char smem[162816];
    u16* wlds = (u16*)smem;                 // 147456 B frag slots
    float* gl = (float*)(smem + 147456);    // [12 waves][16 la][20] f32
    const int tid = threadIdx.x;
    const int bid = blockIdx.x;
    const int wv = tid >> 6, lane = tid & 63;
    const int la = lane & 15, lg = lane >> 4;

    int role, jb;
    if (bid < 72) { role = 0; jb = bid; }
    else if (bid < 216) { role = 1; jb = bid - 72; }
    else { role = 2; jb = bid - 216; }

    int* bar0 = bar;          // 8 groups: gc[0..127], root@128, gen@144
    int* bar1 = bar + 256;    // 16 groups: gc[0..255], root@256, gen@272
    int* bar2 = bar + 768;    // 1 group
    int* g0 = bar0 + 144;
    int* g1 = bar1 + 272;

    // ---- one-time weight preload (roles 0,1) ----
    if (role == 0) {
        for (int s = tid; s < 4 * 36 * 64; s += 768) {
            int ln = s & 63, kt = (s >> 6) % 36, nt = s / (36 * 64);
            int row = nt * 1152 + jb * 16 + (ln & 15);
            int col = kt * 32 + (ln >> 4) * 8;
            *(s16x8*)(wlds + (size_t)s * 8) =
                *(const s16x8*)(Whh0p + (size_t)row * 1152 + col);
        }
    } else if (role == 1) {
        for (int s = tid; s < 2 * 72 * 64; s += 768) {
            int ln = s & 63, kt = (s >> 6) % 72, nt = s / (72 * 64);
            int lr = nt * 16 + (ln & 15);
            int row = (lr >> 3) * 1152 + jb * 8 + (lr & 7);
            int col8 = (ln >> 4) * 8;
            const u16* src = (kt < 36)
                ? Wih1p + (size_t)row * 1152 + kt * 32 + col8
                : Whh1p + (size_t)row * 1152 + (kt - 36) * 32 + col8;
            *(s16x8*)(wlds + (size_t)s * 8) = *(const s16x8*)src;
        }
    }
    __syncthreads();

    float c_reg = 0.f;
    for (int t = 0; t < SEQL; ++t) {
        if (role == 1) waitgen(g0, t + 1);       // ys0s slot t+1 ready
        else if (role == 2) waitgen(g1, t + 1);  // ys1s slot t+1 ready

        f32x4 acc = {0.f, 0.f, 0.f, 0.f};
        if (role == 0) {
            int nt = wv / 3, kg = wv - nt * 3;
            const u16* ar = ys0s + ((size_t)t * 16 + la) * 1152 + lg * 8;
            for (int kt = kg * 12; kt < kg * 12 + 12; ++kt) {
                s16x8 a = *(const s16x8*)(ar + kt * 32);
                s16x8 b = *(const s16x8*)(wlds + ((size_t)(nt * 36 + kt) * 64 + lane) * 8);
                acc = __builtin_amdgcn_mfma_f32_16x16x32_bf16(a, b, acc, 0, 0, 0);
            }
            *(f32x4*)(gl + wv * 320 + la * 20 + lg * 4) = acc;
        } else if (role == 1) {
            int nt = wv / 6, kg = wv - nt * 6;
            const u16* ax = ys0s + ((size_t)(t + 1) * 16 + la) * 1152 + lg * 8;
            const u16* ah = ys1s + ((size_t)t * 16 + la) * 1152 + lg * 8;
            for (int kt = kg * 12; kt < kg * 12 + 12; ++kt) {
                s16x8 a = (kt < 36) ? *(const s16x8*)(ax + kt * 32)
                                    : *(const s16x8*)(ah + (kt - 36) * 32);
                s16x8 b = *(const s16x8*)(wlds + ((size_t)(nt * 72 + kt) * 64 + lane) * 8);
                acc = __builtin_amdgcn_mfma_f32_16x16x32_bf16(a, b, acc, 0, 0, 0);
            }
            *(f32x4*)(gl + wv * 320 + la * 20 + lg * 4) = acc;
        } else {
            int nt = wv / 3, kg = wv - nt * 3;
            int k0 = (kg * 49) / 3, k1 = ((kg + 1) * 49) / 3;
            const u16* ax = ys1s + ((size_t)(t + 1) * 16 + la) * 1152 + lg * 8;
            const u16* ah = ys2s + ((size_t)t * 16 + la) * 416 + lg * 8;
            int wr = nt * 416 + jb * 16 + la;
            for (int kt = k0; kt < k1; ++kt) {
                s16x8 a, b;
                if (kt < 36) {
                    a = *(const s16x8*)(ax + kt * 32);
                    b = *(const s16x8*)(Wih2p + (size_t)wr * 1152 + kt * 32 + lg * 8);
                } else {
                    a = *(const s16x8*)(ah + (kt - 36) * 32);
                    b = *(const s16x8*)(Whh2p + (size_t)wr * 416 + (kt - 36) * 32 + lg * 8);
                }
                acc = __builtin_amdgcn_mfma_f32_16x16x32_bf16(a, b, acc, 0, 0, 0);
            }
            *(f32x4*)(gl + wv * 320 + la * 20 + lg * 4) = acc;
        }
        __syncthreads();
        // ---- activation ----
        if (role == 1) {
            if (tid < 128) {
                int u = tid & 7, tb = tid >> 3;
                int ug = jb * 8 + u;
                float gv[4];
#pragma unroll
                for (int g = 0; g < 4; ++g) {
                    int lr = g * 8 + u;
                    int nt = lr >> 4, li = lr & 15;
                    float s = 0.f;
#pragma unroll
                    for (int kg = 0; kg < 6; ++kg)
                        s += gl[(nt * 6 + kg) * 320 + li * 20 + tb];
                    gv[g] = s + bias1v[g * 1152 + ug];
                }
                float cprev = (t == 0) ? ((ug < 1150) ? c01[tb * 1150 + ug] : 0.f) : c_reg;
                float si = 1.f / (1.f + expf(-gv[0]));
                float sf = 1.f / (1.f + expf(-gv[1]));
                float so = 1.f / (1.f + expf(-gv[3]));
                float cn = sf * cprev + si * tanhf(gv[2]);
                float hn = so * tanhf(cn);
                c_reg = cn;
                if (ug < 1150) {
                    ys1s[((size_t)(t + 1) * 16 + tb) * 1152 + ug] = f2b(hn);
                    if (t == SEQL - 1) { oh2[tb * 1150 + ug] = hn; oc2[tb * 1150 + ug] = cn; }
                }
            }
        } else if (tid < 256) {
            int u = tid & 15, tb = tid >> 4;
            int ug = jb * 16 + u;
            float gv[4];
#pragma unroll
            for (int g = 0; g < 4; ++g) {
                float s = 0.f;
#pragma unroll
                for (int kg = 0; kg < 3; ++kg)
                    s += gl[(g * 3 + kg) * 320 + u * 20 + tb];
                gv[g] = s + ((role == 0)
                             ? xW0[((size_t)t * 16 + tb) * 4608 + g * 1152 + ug]
                             : bias2v[g * 416 + ug]);
            }
            int N = (role == 0) ? 1150 : 400;
            const float* c0i = (role == 0) ? c00 : c02;
            float cprev = (t == 0) ? ((ug < N) ? c0i[tb * N + ug] : 0.f) : c_reg;
            float si = 1.f / (1.f + expf(-gv[0]));
            float sf = 1.f / (1.f + expf(-gv[1]));
            float so = 1.f / (1.f + expf(-gv[3]));
            float cn = sf * cprev + si * tanhf(gv[2]);
            float hn = so * tanhf(cn);
            c_reg = cn;
            if (ug < N) {
                if (role == 0) {
                    ys0s[((size_t)(t + 1) * 16 + tb) * 1152 + ug] = f2b(hn);
                    if (t == SEQL - 1) { oh1[tb * 1150 + ug] = hn; oc1[tb * 1150 + ug] = cn; }
                } else {
                    ys2s[((size_t)(t + 1) * 16 + tb) * 416 + ug] = f2b(hn);
                    if (t == SEQL - 1) { oh3[tb * 400 + ug] = hn; oc3[tb * 400 + ug] = cn; }
                }
            }
        }
        if (role == 0) rolebar(bar0, 72, 8, jb, t);
        else if (role == 1) rolebar(bar1, 144, 16, jb, t);
        else rolebar(bar2, 26, 1, jb, t);
    }
}

// ---------- fused CNF: round-2-proven structure, 32 rows/block, 2 blocks/CU ----------
__global__ __launch_bounds__(512, 4) void cnf_k(const float* __restrict__ emb,
                                                const u16* __restrict__ Wxp,
                                                const float* __restrict__ wt,
                                                const float* __restrict__ bv,
                                                const float* __restrict__ dwx,
                                                float* __restrict__ dl) {
    __shared__ float z0s[32 * CZS];
    __shared__ __align__(16) u16 zi[32 * 416];
    const int tid = threadIdx.x;
    const int m0 = blockIdx.x * 32;

    for (int idx = tid; idx < 32 * 416; idx += 512) {
        int r = idx / 416, cc = idx - r * 416;
        int row = m0 + r;
        float v = (cc < 400 && row < NTOK) ? emb[(size_t)row * 400 + cc] : 0.f;
        if (cc < 416) z0s[r * CZS + cc] = v;
        *(u16*)((char*)zi + czoff(r, cc * 2)) = f2b(v);
    }

    const int wv = tid >> 6, lane = tid & 63;
    const int la = lane & 15, lg = lane >> 4;
    const int lk = lg * 8;
    const int Qw = (wv == 0) ? 4 : 3;
    const int ntb = (wv == 0) ? 0 : 4 + (wv - 1) * 3;

    float wtq[4], bq[4], dwq[4];
#pragma unroll
    for (int q = 0; q < 4; ++q) {
        if (q < Qw) {
            int col = (ntb + q) * 16 + la;
            wtq[q] = wt[col]; bq[q] = bv[col]; dwq[q] = dwx[col];
        } else { wtq[q] = 0.f; bq[q] = 0.f; dwq[q] = 0.f; }
    }
    __syncthreads();

    const float dt = 1.f / ODE_STEPS;
    const f32x4 Z4 = {0.f, 0.f, 0.f, 0.f};
    float Aacc[2][4][4];
#pragma unroll
    for (int m = 0; m < 2; ++m)
#pragma unroll
        for (int q = 0; q < 4; ++q)
#pragma unroll
            for (int r = 0; r < 4; ++r) Aacc[m][q][r] = 0.f;
    float divp[2][4];
#pragma unroll
    for (int m = 0; m < 2; ++m)
#pragma unroll
        for (int r = 0; r < 4; ++r) divp[m][r] = 0.f;

#pragma unroll 1
    for (int st = 0; st < ODE_STEPS; ++st) {
        float t0 = st * dt;
#pragma unroll 1
        for (int s = 0; s < 4; ++s) {
            float ts = t0 + ((s == 0) ? 0.f : (s == 3) ? dt : 0.5f * dt);
            float wgt = (s == 1 || s == 2) ? 2.f : 1.f;
            float cs = (s == 2) ? dt : 0.5f * dt;
            f32x4 pre[2][4];
#pragma unroll
            for (int m = 0; m < 2; ++m)
#pragma unroll
                for (int q = 0; q < 4; ++q) pre[m][q] = Z4;
#pragma unroll 1
            for (int kk = 0; kk < 13; ++kk) {
                s16x8 b[4];
#pragma unroll
                for (int q = 0; q < 4; ++q)
                    if (q < Qw)
                        b[q] = *(const s16x8*)(Wxp + (size_t)((ntb + q) * 16 + la) * 416 +
                                               kk * 32 + lk);
#pragma unroll
                for (int m = 0; m < 2; ++m) {
                    int row = m * 16 + la;
                    s16x8 a = *(const s16x8*)((const char*)zi + czoff(row, kk * 64 + lg * 16));
#pragma unroll
                    for (int q = 0; q < 4; ++q)
                        if (q < Qw)
                            pre[m][q] = __builtin_amdgcn_mfma_f32_16x16x32_bf16(
                                a, b[q], pre[m][q], 0, 0, 0);
                }
            }
            __syncthreads();
#pragma unroll
            for (int m = 0; m < 2; ++m) {
#pragma unroll
                for (int q = 0; q < 4; ++q) {
                    if (q >= Qw) continue;
                    int col = (ntb + q) * 16 + la;
#pragma unroll
                    for (int r = 0; r < 4; ++r) {
                        int row = m * 16 + lg * 4 + r;
                        float pv = pre[m][q][r] + ts * wtq[q] + bq[q];
                        float kz = fmaxf(pv, 0.f);
                        if (pv > 0.f) divp[m][r] += dwq[q] * wgt;
                        float An = Aacc[m][q][r] + wgt * kz;
                        float ev;
                        if (s < 3) {
                            Aacc[m][q][r] = An;
                            ev = z0s[row * CZS + col] + cs * kz;
                        } else {
                            float zn = z0s[row * CZS + col] + (dt / 6.f) * An;
                            z0s[row * CZS + col] = zn;
                            Aacc[m][q][r] = 0.f;
                            ev = zn;
                        }
                        *(u16*)((char*)zi + czoff(row, col * 2)) = f2b(ev);
                    }
                }
            }
            __syncthreads();
        }
    }

#pragma unroll
    for (int m = 0; m < 2; ++m)
#pragma unroll
        for (int r = 0; r < 4; ++r) {
            float v = divp[m][r];
            v += __shfl_xor(v, 1, 64);
            v += __shfl_xor(v, 2, 64);
            v += __shfl_xor(v, 4, 64);
            v += __shfl_xor(v, 8, 64);
            divp[m][r] = v;
        }
    float* dsc = (float*)zi;
    if (la == 0) {
#pragma unroll
        for (int m = 0; m < 2; ++m)
#pragma unroll
            for (int r = 0; r < 4; ++r)
                dsc[wv * 32 + m * 16 + lg * 4 + r] = divp[m][r];
    }
    __syncthreads();
    for (int row = tid; row < 32; row += 512) {
        float s = 0.f;
#pragma unroll
        for (int w = 0; w < 8; ++w) s += dsc[w * 32 + row];
        if (m0 + row < NTOK) dl[m0 + row] = -(dt / 6.f) * s;
    }
}

// ---------- in-place log(softmax(x)+1e-8) per row ----------
__global__ void logsoftmax_k(float* __restrict__ L, int n) {
    const int row = blockIdx.x;
    float* R = L + (size_t)row * n;
    const int tid = threadIdx.x;
    float mx = -INFINITY, s = 0.f;
    for (int c = tid; c < n; c += 256) {
        float v = R[c];
        float nm = fmaxf(mx, v);
        s = s * expf(mx - nm) + expf(v - nm);
        mx = nm;
    }
#pragma unroll
    for (int off = 1; off < 64; off <<= 1) {
        float om = __shfl_xor(mx, off, 64);
        float os = __shfl_xor(s, off, 64);
        float nm = fmaxf(mx, om);
        s = s * expf(mx - nm) + os * expf(om - nm);
        mx = nm;
    }
    __shared__ float smx[4], ssm[4];
    if ((tid & 63) == 0) { smx[tid >> 6] = mx; ssm[tid >> 6] = s; }
    __syncthreads();
    float bm = fmaxf(fmaxf(smx[0], smx[1]), fmaxf(smx[2], smx[3]));
    float bs = ssm[0] * expf(smx[0] - bm) + ssm[1] * expf(smx[1] - bm) +
               ssm[2] * expf(smx[2] - bm) + ssm[3] * expf(smx[3] - bm);
    float lz = logf(bs);
    for (int c = tid; c < n; c += 256) {
        float v = R[c];
        R[c] = logf(expf(v - bm) + 1e-8f * bs) - lz;
    }
}

extern "C" void kernel_launch(void* const* d_in, const int* in_sizes, int n_in,
                              void* d_out, int out_size, void* d_ws, size_t ws_size,
                              hipStream_t stream) {
    const int*   tokens = (const int*)d_in[0];
    const float* h00 = (const float*)d_in[1];
    const float* c00 = (const float*)d_in[2];
    const float* h01 = (const float*)d_in[3];
    const float* c01 = (const float*)d_in[4];
    const float* h02 = (const float*)d_in[5];
    const float* c02 = (const float*)d_in[6];
    const float* embW = (const float*)d_in[7];
    const float* Wih0 = (const float*)d_in[8];
    const float* Whh0 = (const float*)d_in[9];
    const float* bih0 = (const float*)d_in[10];
    const float* bhh0 = (const float*)d_in[11];
    const float* Wih1 = (const float*)d_in[12];
    const float* Whh1 = (const float*)d_in[13];
    const float* bih1 = (const float*)d_in[14];
    const float* bhh1 = (const float*)d_in[15];
    const float* Wih2 = (const float*)d_in[16];
    const float* Whh2 = (const float*)d_in[17];
    const float* bih2 = (const float*)d_in[18];
    const float* bhh2 = (const float*)d_in[19];
    const float* cnfW = (const float*)d_in[20];
    const float* cnfb = (const float*)d_in[21];
    float* out = (float*)d_out;

    char* p = (char*)d_ws;
    auto alloc = [&](size_t bytes) -> void* {
        void* r = (void*)p;
        p += (bytes + 255) & ~(size_t)255;
        return r;
    };
    u16*   emb_p = (u16*)alloc((size_t)33280 * 416 * 2);
    u16*   x0    = (u16*)alloc((size_t)1152 * 416 * 2);
    u16*   ys0s  = (u16*)alloc((size_t)1136 * 1152 * 2);
    u16*   ys1s  = (u16*)alloc((size_t)1136 * 1152 * 2);
    u16*   ys2s  = (u16*)alloc((size_t)1184 * 416 * 2);   // +pad for gemm overread
    float* xW    = (float*)alloc((size_t)1120 * 4608 * 4);
    u16*   Wih0p = (u16*)alloc((size_t)4608 * 416 * 2);
    u16*   Whh0p = (u16*)alloc((size_t)4608 * 1152 * 2);
    u16*   Wih1p = (u16*)alloc((size_t)4608 * 1152 * 2);
    u16*   Whh1p = (u16*)alloc((size_t)4608 * 1152 * 2);
    u16*   Wih2p = (u16*)alloc((size_t)1664 * 1152 * 2);
    u16*   Whh2p = (u16*)alloc((size_t)1664 * 416 * 2);
    float* bias0 = (float*)alloc((size_t)4608 * 4);
    float* bias1 = (float*)alloc((size_t)4608 * 4);
    float* bias2 = (float*)alloc((size_t)1664 * 4);
    u16*   Wxp   = (u16*)alloc((size_t)416 * 416 * 2);
    float* wtv   = (float*)alloc((size_t)400 * 4);
    float* dwx   = (float*)alloc((size_t)400 * 4);
    float* dl    = (float*)alloc((size_t)NTOK * 4);
    float* e2    = (float*)alloc((size_t)NTOK * 4);
    float* uvec  = (float*)alloc((size_t)NTOK * 4);
    int*   bar   = (int*)alloc(4096);

    size_t OM = (size_t)SEQL * 16 * NTOK;
    float* oh1 = out + OM;
    float* oc1 = oh1 + 16 * 1150;
    float* oh2 = oc1 + 16 * 1150;
    float* oc2 = oh2 + 16 * 1150;
    float* oh3 = oc2 + 16 * 1150;
    float* oc3 = oh3 + 16 * 400;

    hipMemsetAsync(bar, 0, 4096, stream);
    hipMemsetAsync(ys0s, 0, (size_t)1136 * 1152 * 2, stream);
    hipMemsetAsync(ys1s, 0, (size_t)1136 * 1152 * 2, stream);
    hipMemsetAsync(ys2s, 0, (size_t)1184 * 416 * 2, stream);

    cvt_pad_k<<<2048, 256, 0, stream>>>(Wih0, Wih0p, 4, 1150, 1152, 400, 416, 400, 0);
    cvt_pad_k<<<2048, 256, 0, stream>>>(Whh0, Whh0p, 4, 1150, 1152, 1150, 1152, 1150, 0);
    cvt_pad_k<<<2048, 256, 0, stream>>>(Wih1, Wih1p, 4, 1150, 1152, 1150, 1152, 1150, 0);
    cvt_pad_k<<<2048, 256, 0, stream>>>(Whh1, Whh1p, 4, 1150, 1152, 1150, 1152, 1150, 0);
    cvt_pad_k<<<2048, 256, 0, stream>>>(Wih2, Wih2p, 4, 400, 416, 1150, 1152, 1150, 0);
    cvt_pad_k<<<2048, 256, 0, stream>>>(Whh2, Whh2p, 4, 400, 416, 400, 416, 400, 0);
    cvt_pad_k<<<2048, 256, 0, stream>>>(embW, emb_p, 1, 33278, 33280, 400, 416, 400, 0);
    cvt_pad_k<<<2048, 256, 0, stream>>>(cnfW, Wxp, 1, 400, 416, 400, 416, 401, 1);
    bias_k<<<(4 * 1152 + 255) / 256, 256, 0, stream>>>(bih0, bhh0, bias0, 1150, 1152);
    bias_k<<<(4 * 1152 + 255) / 256, 256, 0, stream>>>(bih1, bhh1, bias1, 1150, 1152);
    bias_k<<<(4 * 416 + 255) / 256, 256, 0, stream>>>(bih2, bhh2, bias2, 400, 416);
    wtdwx_k<<<2, 256, 0, stream>>>(cnfW, wtv, dwx);
    rowsumsq_k<<<NTOK, 64, 0, stream>>>(embW, e2, 400);

    // h0 -> ys slot 0
    h0cvt_k<<<(16 * 1152 + 255) / 256, 256, 0, stream>>>(h00, ys0s, 1150, 1152);
    h0cvt_k<<<(16 * 1152 + 255) / 256, 256, 0, stream>>>(h01, ys1s, 1150, 1152);
    h0cvt_k<<<(16 * 416 + 255) / 256, 256, 0, stream>>>(h02, ys2s, 400, 416);

    // CNF (independent): 32 rows/block, 2 blocks/CU
    cnf_k<<<1040, 512, 0, stream>>>(embW, Wxp, wtv, cnfb, dwx, dl);
    ucomb_k<<<(NTOK + 255) / 256, 256, 0, stream>>>(e2, dl, uvec);

    // embedding + xW0 = x0 @ Wih0^T + (bih0+bhh0)
    embed_k<<<(1152 * 416 + 255) / 256, 256, 0, stream>>>(tokens, embW, x0);
    gemm_bt_k<<<dim3(72, 18), 256, 0, stream>>>(x0, Wih0p, xW, 416, 416, 416, 4608,
                                                1120, 4608, bias0);

    // persistent-weight LSTM (3 decoupled role pipelines)
    lstm_k<<<NBLK, 768, 0, stream>>>(
        c00, c01, c02, Whh0p, Wih1p, Whh1p, Wih2p, Whh2p,
        xW, bias2, bias1, ys0s, ys1s, ys2s,
        oh1, oc1, oh2, oc2, oh3, oc3, bar);

    // logits into d_out, then in-place log-softmax
    gemm_bt_k<<<dim3(520, 18), 256, 0, stream>>>(ys2s + (size_t)16 * 416, emb_p, out,
                                                 416, 416, 416, NTOK, 1120, NTOK, uvec);
    logsoftmax_k<<<1120, 256, 0, stream>>>(out, NTOK);
}

// Round 10
// 2992.792 us; speedup vs baseline: 1.9328x; 1.0653x over previous
//
#include <hip/hip_runtime.h>
#include <hip/hip_bf16.h>
#include <math.h>

#define SEQL 70
#define NTOK 33278
#define ODE_STEPS 8
#define NBLK 242
#define CZS 418

typedef __attribute__((ext_vector_type(4))) float f32x4;
typedef __attribute__((ext_vector_type(8))) short s16x8;
typedef unsigned short u16;

__device__ __forceinline__ u16 f2b(float f) {
    union { float f; unsigned int u; } a; a.f = f;
    unsigned int u = a.u;
    return (u16)((u + 0x7FFFu + ((u >> 16) & 1u)) >> 16);
}
__device__ __forceinline__ float b2f(u16 s) {
    union { unsigned int u; float f; } a; a.u = ((unsigned int)s) << 16;
    return a.f;
}

// CNF zi swizzle: row is 832 B = 6.5 x 128B groups; tail [768,832) swizzles bits 4-5 only.
__device__ __forceinline__ unsigned czoff(int row, int colb) {
    unsigned s = ((colb < 768 ? (row & 7) : (row & 3)) << 4);
    return (unsigned)(row * 832 + (colb ^ (int)s));
}

// ---------- prep kernels ----------
__global__ void cvt_pad_k(const float* __restrict__ src, u16* __restrict__ dst,
                          int G, int Nin, int Nop, int Kin, int Kp, int rs, int co) {
    size_t total = (size_t)G * Nop * Kp;
    for (size_t idx = (size_t)blockIdx.x * 256 + threadIdx.x; idx < total;
         idx += (size_t)gridDim.x * 256) {
        int k = (int)(idx % Kp);
        size_t t2 = idx / Kp;
        int j = (int)(t2 % Nop);
        int g = (int)(t2 / Nop);
        float v = 0.f;
        if (j < Nin && k < Kin) v = src[((size_t)g * Nin + j) * rs + co + k];
        dst[idx] = f2b(v);
    }
}

__global__ void bias_k(const float* __restrict__ bih, const float* __restrict__ bhh,
                       float* __restrict__ o, int Nin, int Nop) {
    int idx = blockIdx.x * 256 + threadIdx.x;
    if (idx >= 4 * Nop) return;
    int g = idx / Nop, j = idx % Nop;
    o[idx] = (j < Nin) ? (bih[g * Nin + j] + bhh[g * Nin + j]) : 0.f;
}

__global__ void wtdwx_k(const float* __restrict__ cw, float* __restrict__ wt,
                        float* __restrict__ dwx) {
    int i = blockIdx.x * 256 + threadIdx.x;
    if (i < 400) {
        wt[i]  = cw[(size_t)i * 401];
        dwx[i] = cw[(size_t)i * 401 + 1 + i];
    }
}

__global__ void h0cvt_k(const float* __restrict__ h0, u16* __restrict__ hb, int N, int Kp) {
    int idx = blockIdx.x * 256 + threadIdx.x;
    if (idx >= 16 * Kp) return;
    int b = idx / Kp, k = idx % Kp;
    hb[idx] = f2b(k < N ? h0[b * N + k] : 0.f);
}

__global__ void embed_k(const int* __restrict__ tok, const float* __restrict__ emb,
                        u16* __restrict__ x0) {
    int idx = blockIdx.x * 256 + threadIdx.x;
    if (idx >= 1152 * 416) return;
    int r = idx / 416, k = idx - r * 416;
    float v = 0.f;
    if (r < SEQL * 16 && k < 400) v = emb[(size_t)tok[r] * 400 + k];
    x0[idx] = f2b(v);
}

__global__ void rowsumsq_k(const float* __restrict__ X, float* __restrict__ o, int K) {
    int r = blockIdx.x;
    const float* xr = X + (size_t)r * K;
    int lane = threadIdx.x;
    float s = 0.f;
    for (int k = lane; k < K; k += 64) { float v = xr[k]; s += v * v; }
#pragma unroll
    for (int off = 1; off < 64; off <<= 1) s += __shfl_xor(s, off, 64);
    if (lane == 0) o[r] = s;
}

__global__ void ucomb_k(const float* __restrict__ e2, const float* __restrict__ dl,
                        float* __restrict__ u) {
    int i = blockIdx.x * 256 + threadIdx.x;
    if (i < NTOK) u[i] = -0.5f * e2[i] - dl[i];
}

// ---------- GEMM: C[M,N](fp32) = A[M,Kp](bf16) * B[N,Kp]^T(bf16) (+ u[n]) ----------
__global__ void gemm_bt_k(const u16* __restrict__ A, const u16* __restrict__ B,
                          float* __restrict__ C, int Kp, int lda, int ldb, int ldc,
                          int Mreal, int Nreal, const float* __restrict__ uvec) {
    const int tid = threadIdx.x;
    const int wid = tid >> 6, lane = tid & 63;
    const int la = lane & 15, lk = (lane >> 4) * 8;
    const int m0 = blockIdx.y * 64 + wid * 16;
    const int n0 = blockIdx.x * 64;
    const f32x4 Z4 = {0.f, 0.f, 0.f, 0.f};
    f32x4 acc[4] = {Z4, Z4, Z4, Z4};
    const u16* Ar = A + (size_t)(m0 + la) * lda + lk;
    const u16* Br = B + (size_t)(n0 + la) * ldb + lk;
    for (int k = 0; k < Kp; k += 32) {
        s16x8 a = *(const s16x8*)(Ar + k);
#pragma unroll
        for (int nt = 0; nt < 4; ++nt) {
            s16x8 b = *(const s16x8*)(Br + (size_t)nt * 16 * ldb + k);
            acc[nt] = __builtin_amdgcn_mfma_f32_16x16x32_bf16(a, b, acc[nt], 0, 0, 0);
        }
    }
    const int mr = m0 + (lane >> 4) * 4;
#pragma unroll
    for (int nt = 0; nt < 4; ++nt) {
        int cc = n0 + nt * 16 + la;
        if (cc >= Nreal) continue;
        float uv = uvec ? uvec[cc] : 0.f;
#pragma unroll
        for (int r = 0; r < 4; ++r) {
            int rr = mr + r;
            if (rr < Mreal) C[(size_t)rr * ldc + cc] = acc[nt][r] + uv;
        }
    }
}

// ---------- flat per-role barrier: same-line RMWs pipeline at the home L2 ----------
// Spin is RELAXED (no invalidate storm); one ACQUIRE after exit pulls cross-XCD data.
__device__ __forceinline__ void flatbar(int* cnt, int* gen, int nb, int iter) {
    __syncthreads();
    if (threadIdx.x == 0) {
        int old = __hip_atomic_fetch_add(cnt, 1, __ATOMIC_ACQ_REL, __HIP_MEMORY_SCOPE_AGENT);
        if ((old % nb) == nb - 1)
            __hip_atomic_fetch_add(gen, 1, __ATOMIC_ACQ_REL, __HIP_MEMORY_SCOPE_AGENT);
        while (__hip_atomic_load(gen, __ATOMIC_RELAXED, __HIP_MEMORY_SCOPE_AGENT) <= iter)
            __builtin_amdgcn_s_sleep(2);
        (void)__hip_atomic_load(gen, __ATOMIC_ACQUIRE, __HIP_MEMORY_SCOPE_AGENT);
    }
    __syncthreads();
}
__device__ __forceinline__ void waitgen(int* gen, int needed) {
    if (threadIdx.x == 0) {
        while (__hip_atomic_load(gen, __ATOMIC_RELAXED, __HIP_MEMORY_SCOPE_AGENT) < needed)
            __builtin_amdgcn_s_sleep(2);
        (void)__hip_atomic_load(gen, __ATOMIC_ACQUIRE, __HIP_MEMORY_SCOPE_AGENT);
    }
    __syncthreads();
}

// ---------- persistent-weight 3-layer LSTM, decoupled role pipelines ----------
__global__ __launch_bounds__(768, 3) void lstm_k(
    const float* __restrict__ c00, const float* __restrict__ c01,
    const float* __restrict__ c02,
    const u16* __restrict__ Whh0p, const u16* __restrict__ Wih1p,
    const u16* __restrict__ Whh1p, const u16* __restrict__ Wih2p,
    const u16* __restrict__ Whh2p,
    const float* __restrict__ xW0, const float* __restrict__ bias2v,
    const float* __restrict__ bias1v,
    u16* __restrict__ ys0s, u16* __restrict__ ys1s, u16* __restrict__ ys2s,
    float* __restrict__ oh1, float* __restrict__ oc1,
    float* __restrict__ oh2, float* __restrict__ oc2,
    float* __restrict__ oh3, float* __restrict__ oc3,
    int* __restrict__ bar)
{
    __shared__ __align__(16) char smem[162816];
    u16* wlds = (u16*)smem;                 // 147456 B frag slots
    float* gl = (float*)(smem + 147456);    // [12 waves][16 la][20] f32
    const int tid = threadIdx.x;
    const int bid = blockIdx.x;
    const int wv = tid >> 6, lane = tid & 63;
    const int la = lane & 15, lg = lane >> 4;

    int role, jb;
    if (bid < 72) { role = 0; jb = bid; }
    else if (bid < 216) { role = 1; jb = bid - 72; }
    else { role = 2; jb = bid - 216; }

    // flat barrier lines (64B apart): role r: cnt@bar[r*32], gen@bar[r*32+16]
    int* c0 = bar;        int* g0 = bar + 16;
    int* c1 = bar + 32;   int* g1 = bar + 48;
    int* c2 = bar + 64;   int* g2 = bar + 80;

    // ---- one-time weight preload (roles 0,1) ----
    if (role == 0) {
        for (int s = tid; s < 4 * 36 * 64; s += 768) {
            int ln = s & 63, kt = (s >> 6) % 36, nt = s / (36 * 64);
            int row = nt * 1152 + jb * 16 + (ln & 15);
            int col = kt * 32 + (ln >> 4) * 8;
            *(s16x8*)(wlds + (size_t)s * 8) =
                *(const s16x8*)(Whh0p + (size_t)row * 1152 + col);
        }
    } else if (role == 1) {
        for (int s = tid; s < 2 * 72 * 64; s += 768) {
            int ln = s & 63, kt = (s >> 6) % 72, nt = s / (72 * 64);
            int lr = nt * 16 + (ln & 15);
            int row = (lr >> 3) * 1152 + jb * 8 + (lr & 7);
            int col8 = (ln >> 4) * 8;
            const u16* src = (kt < 36)
                ? Wih1p + (size_t)row * 1152 + kt * 32 + col8
                : Whh1p + (size_t)row * 1152 + (kt - 36) * 32 + col8;
            *(s16x8*)(wlds + (size_t)s * 8) = *(const s16x8*)src;
        }
    }
    __syncthreads();

    float c_reg = 0.f;
    for (int t = 0; t < SEQL; ++t) {
        if (role == 1) waitgen(g0, t + 1);       // ys0s slot t+1 ready
        else if (role == 2) waitgen(g1, t + 1);  // ys1s slot t+1 ready

        f32x4 acc = {0.f, 0.f, 0.f, 0.f};
        if (role == 0) {
            int nt = wv / 3, kg = wv - nt * 3;
            const u16* ar = ys0s + ((size_t)t * 16 + la) * 1152 + lg * 8;
            for (int kt = kg * 12; kt < kg * 12 + 12; ++kt) {
                s16x8 a = *(const s16x8*)(ar + kt * 32);
                s16x8 b = *(const s16x8*)(wlds + ((size_t)(nt * 36 + kt) * 64 + lane) * 8);
                acc = __builtin_amdgcn_mfma_f32_16x16x32_bf16(a, b, acc, 0, 0, 0);
            }
            *(f32x4*)(gl + wv * 320 + la * 20 + lg * 4) = acc;
        } else if (role == 1) {
            int nt = wv / 6, kg = wv - nt * 6;
            const u16* ax = ys0s + ((size_t)(t + 1) * 16 + la) * 1152 + lg * 8;
            const u16* ah = ys1s + ((size_t)t * 16 + la) * 1152 + lg * 8;
            for (int kt = kg * 12; kt < kg * 12 + 12; ++kt) {
                s16x8 a = (kt < 36) ? *(const s16x8*)(ax + kt * 32)
                                    : *(const s16x8*)(ah + (kt - 36) * 32);
                s16x8 b = *(const s16x8*)(wlds + ((size_t)(nt * 72 + kt) * 64 + lane) * 8);
                acc = __builtin_amdgcn_mfma_f32_16x16x32_bf16(a, b, acc, 0, 0, 0);
            }
            *(f32x4*)(gl + wv * 320 + la * 20 + lg * 4) = acc;
        } else {
            int nt = wv / 3, kg = wv - nt * 3;
            int k0 = (kg * 49) / 3, k1 = ((kg + 1) * 49) / 3;
            const u16* ax = ys1s + ((size_t)(t + 1) * 16 + la) * 1152 + lg * 8;
            const u16* ah = ys2s + ((size_t)t * 16 + la) * 416 + lg * 8;
            int wr = nt * 416 + jb * 16 + la;
            for (int kt = k0; kt < k1; ++kt) {
                s16x8 a, b;
                if (kt < 36) {
                    a = *(const s16x8*)(ax + kt * 32);
                    b = *(const s16x8*)(Wih2p + (size_t)wr * 1152 + kt * 32 + lg * 8);
                } else {
                    a = *(const s16x8*)(ah + (kt - 36) * 32);
                    b = *(const s16x8*)(Whh2p + (size_t)wr * 416 + (kt - 36) * 32 + lg * 8);
                }
                acc = __builtin_amdgcn_mfma_f32_16x16x32_bf16(a, b, acc, 0, 0, 0);
            }
            *(f32x4*)(gl + wv * 320 + la * 20 + lg * 4) = acc;
        }
        __syncthreads();
        // ---- activation ----
        if (role == 1) {
            if (tid < 128) {
                int u = tid & 7, tb = tid >> 3;
                int ug = jb * 8 + u;
                float gv[4];
#pragma unroll
                for (int g = 0; g < 4; ++g) {
                    int lr = g * 8 + u;
                    int nt = lr >> 4, li = lr & 15;
                    float s = 0.f;
#pragma unroll
                    for (int kg = 0; kg < 6; ++kg)
                        s += gl[(nt * 6 + kg) * 320 + li * 20 + tb];
                    gv[g] = s + bias1v[g * 1152 + ug];
                }
                float cprev = (t == 0) ? ((ug < 1150) ? c01[tb * 1150 + ug] : 0.f) : c_reg;
                float si = 1.f / (1.f + expf(-gv[0]));
                float sf = 1.f / (1.f + expf(-gv[1]));
                float so = 1.f / (1.f + expf(-gv[3]));
                float cn = sf * cprev + si * tanhf(gv[2]);
                float hn = so * tanhf(cn);
                c_reg = cn;
                if (ug < 1150) {
                    ys1s[((size_t)(t + 1) * 16 + tb) * 1152 + ug] = f2b(hn);
                    if (t == SEQL - 1) { oh2[tb * 1150 + ug] = hn; oc2[tb * 1150 + ug] = cn; }
                }
            }
        } else if (tid < 256) {
            int u = tid & 15, tb = tid >> 4;
            int ug = jb * 16 + u;
            float gv[4];
#pragma unroll
            for (int g = 0; g < 4; ++g) {
                float s = 0.f;
#pragma unroll
                for (int kg = 0; kg < 3; ++kg)
                    s += gl[(g * 3 + kg) * 320 + u * 20 + tb];
                gv[g] = s + ((role == 0)
                             ? xW0[((size_t)t * 16 + tb) * 4608 + g * 1152 + ug]
                             : bias2v[g * 416 + ug]);
            }
            int N = (role == 0) ? 1150 : 400;
            const float* c0i = (role == 0) ? c00 : c02;
            float cprev = (t == 0) ? ((ug < N) ? c0i[tb * N + ug] : 0.f) : c_reg;
            float si = 1.f / (1.f + expf(-gv[0]));
            float sf = 1.f / (1.f + expf(-gv[1]));
            float so = 1.f / (1.f + expf(-gv[3]));
            float cn = sf * cprev + si * tanhf(gv[2]);
            float hn = so * tanhf(cn);
            c_reg = cn;
            if (ug < N) {
                if (role == 0) {
                    ys0s[((size_t)(t + 1) * 16 + tb) * 1152 + ug] = f2b(hn);
                    if (t == SEQL - 1) { oh1[tb * 1150 + ug] = hn; oc1[tb * 1150 + ug] = cn; }
                } else {
                    ys2s[((size_t)(t + 1) * 16 + tb) * 416 + ug] = f2b(hn);
                    if (t == SEQL - 1) { oh3[tb * 400 + ug] = hn; oc3[tb * 400 + ug] = cn; }
                }
            }
        }
        if (role == 0) flatbar(c0, g0, 72, t);
        else if (role == 1) flatbar(c1, g1, 144, t);
        else flatbar(c2, g2, 26, t);
    }
}

// ---------- fused CNF: 64 rows/block, 1024 threads (16 waves, 4/SIMD) ----------
__global__ __launch_bounds__(1024, 4) void cnf_k(const float* __restrict__ emb,
                                                 const u16* __restrict__ Wxp,
                                                 const float* __restrict__ wt,
                                                 const float* __restrict__ bv,
                                                 const float* __restrict__ dwx,
                                                 float* __restrict__ dl) {
    __shared__ float z0s[64 * CZS];
    __shared__ __align__(16) u16 zi[64 * 416];
    const int tid = threadIdx.x;
    const int m0 = blockIdx.x * 64;

    for (int idx = tid; idx < 64 * 416; idx += 1024) {
        int r = idx / 416, cc = idx - r * 416;
        int row = m0 + r;
        float v = (cc < 400 && row < NTOK) ? emb[(size_t)row * 400 + cc] : 0.f;
        z0s[r * CZS + cc] = v;
        *(u16*)((char*)zi + czoff(r, cc * 2)) = f2b(v);
    }

    const int wv = tid >> 6, lane = tid & 63;
    const int la = lane & 15, lg = lane >> 4;
    const int lk = lg * 8;
    const int tb0 = (wv * 25) >> 4;                 // first n-tile of this wave
    const int Qw = (((wv + 1) * 25) >> 4) - tb0;    // 1 or 2 tiles

    float wtq[2], bq[2], dwq[2];
#pragma unroll
    for (int q = 0; q < 2; ++q) {
        if (q < Qw) {
            int col = (tb0 + q) * 16 + la;
            wtq[q] = wt[col]; bq[q] = bv[col]; dwq[q] = dwx[col];
        } else { wtq[q] = 0.f; bq[q] = 0.f; dwq[q] = 0.f; }
    }
    __syncthreads();

    const float dt = 1.f / ODE_STEPS;
    const f32x4 Z4 = {0.f, 0.f, 0.f, 0.f};
    float Aacc[4][2][4];
#pragma unroll
    for (int m = 0; m < 4; ++m)
#pragma unroll
        for (int q = 0; q < 2; ++q)
#pragma unroll
            for (int r = 0; r < 4; ++r) Aacc[m][q][r] = 0.f;
    float divp[4][4];
#pragma unroll
    for (int m = 0; m < 4; ++m)
#pragma unroll
        for (int r = 0; r < 4; ++r) divp[m][r] = 0.f;

#pragma unroll 1
    for (int st = 0; st < ODE_STEPS; ++st) {
        float t0 = st * dt;
#pragma unroll 1
        for (int s = 0; s < 4; ++s) {
            float ts = t0 + ((s == 0) ? 0.f : (s == 3) ? dt : 0.5f * dt);
            float wgt = (s == 1 || s == 2) ? 2.f : 1.f;
            float cs = (s == 2) ? dt : 0.5f * dt;
            f32x4 pre[4][2];
#pragma unroll
            for (int m = 0; m < 4; ++m)
#pragma unroll
                for (int q = 0; q < 2; ++q) pre[m][q] = Z4;
#pragma unroll 1
            for (int kk = 0; kk < 13; ++kk) {
                s16x8 b[2];
#pragma unroll
                for (int q = 0; q < 2; ++q)
                    if (q < Qw)
                        b[q] = *(const s16x8*)(Wxp + (size_t)((tb0 + q) * 16 + la) * 416 +
                                               kk * 32 + lk);
#pragma unroll
                for (int m = 0; m < 4; ++m) {
                    int row = m * 16 + la;
                    s16x8 a = *(const s16x8*)((const char*)zi + czoff(row, kk * 64 + lg * 16));
#pragma unroll
                    for (int q = 0; q < 2; ++q)
                        if (q < Qw)
                            pre[m][q] = __builtin_amdgcn_mfma_f32_16x16x32_bf16(
                                a, b[q], pre[m][q], 0, 0, 0);
                }
            }
            __syncthreads();
#pragma unroll
            for (int m = 0; m < 4; ++m) {
#pragma unroll
                for (int q = 0; q < 2; ++q) {
                    if (q >= Qw) continue;
                    int col = (tb0 + q) * 16 + la;
#pragma unroll
                    for (int r = 0; r < 4; ++r) {
                        int row = m * 16 + lg * 4 + r;
                        float pv = pre[m][q][r] + ts * wtq[q] + bq[q];
                        float kz = fmaxf(pv, 0.f);
                        if (pv > 0.f) divp[m][r] += dwq[q] * wgt;
                        float An = Aacc[m][q][r] + wgt * kz;
                        float ev;
                        if (s < 3) {
                            Aacc[m][q][r] = An;
                            ev = z0s[row * CZS + col] + cs * kz;
                        } else {
                            float zn = z0s[row * CZS + col] + (dt / 6.f) * An;
                            z0s[row * CZS + col] = zn;
                            Aacc[m][q][r] = 0.f;
                            ev = zn;
                        }
                        *(u16*)((char*)zi + czoff(row, col * 2)) = f2b(ev);
                    }
                }
            }
            __syncthreads();
        }
    }

#pragma unroll
    for (int m = 0; m < 4; ++m)
#pragma unroll
        for (int r = 0; r < 4; ++r) {
            float v = divp[m][r];
            v += __shfl_xor(v, 1, 64);
            v += __shfl_xor(v, 2, 64);
            v += __shfl_xor(v, 4, 64);
            v += __shfl_xor(v, 8, 64);
            divp[m][r] = v;
        }
    float* dsc = (float*)zi;
    if (la == 0) {
#pragma unroll
        for (int m = 0; m < 4; ++m)
#pragma unroll
            for (int r = 0; r < 4; ++r)
                dsc[wv * 64 + m * 16 + lg * 4 + r] = divp[m][r];
    }
    __syncthreads();
    for (int row = tid; row < 64; row += 1024) {
        float s = 0.f;
#pragma unroll
        for (int w = 0; w < 16; ++w) s += dsc[w * 64 + row];
        if (m0 + row < NTOK) dl[m0 + row] = -(dt / 6.f) * s;
    }
}

// ---------- in-place log(softmax(x)+1e-8) per row ----------
__global__ void logsoftmax_k(float* __restrict__ L, int n) {
    const int row = blockIdx.x;
    float* R = L + (size_t)row * n;
    const int tid = threadIdx.x;
    float mx = -INFINITY, s = 0.f;
    for (int c = tid; c < n; c += 256) {
        float v = R[c];
        float nm = fmaxf(mx, v);
        s = s * expf(mx - nm) + expf(v - nm);
        mx = nm;
    }
#pragma unroll
    for (int off = 1; off < 64; off <<= 1) {
        float om = __shfl_xor(mx, off, 64);
        float os = __shfl_xor(s, off, 64);
        float nm = fmaxf(mx, om);
        s = s * expf(mx - nm) + os * expf(om - nm);
        mx = nm;
    }
    __shared__ float smx[4], ssm[4];
    if ((tid & 63) == 0) { smx[tid >> 6] = mx; ssm[tid >> 6] = s; }
    __syncthreads();
    float bm = fmaxf(fmaxf(smx[0], smx[1]), fmaxf(smx[2], smx[3]));
    float bs = ssm[0] * expf(smx[0] - bm) + ssm[1] * expf(smx[1] - bm) +
               ssm[2] * expf(smx[2] - bm) + ssm[3] * expf(smx[3] - bm);
    float lz = logf(bs);
    for (int c = tid; c < n; c += 256) {
        float v = R[c];
        R[c] = logf(expf(v - bm) + 1e-8f * bs) - lz;
    }
}

extern "C" void kernel_launch(void* const* d_in, const int* in_sizes, int n_in,
                              void* d_out, int out_size, void* d_ws, size_t ws_size,
                              hipStream_t stream) {
    const int*   tokens = (const int*)d_in[0];
    const float* h00 = (const float*)d_in[1];
    const float* c00 = (const float*)d_in[2];
    const float* h01 = (const float*)d_in[3];
    const float* c01 = (const float*)d_in[4];
    const float* h02 = (const float*)d_in[5];
    const float* c02 = (const float*)d_in[6];
    const float* embW = (const float*)d_in[7];
    const float* Wih0 = (const float*)d_in[8];
    const float* Whh0 = (const float*)d_in[9];
    const float* bih0 = (const float*)d_in[10];
    const float* bhh0 = (const float*)d_in[11];
    const float* Wih1 = (const float*)d_in[12];
    const float* Whh1 = (const float*)d_in[13];
    const float* bih1 = (const float*)d_in[14];
    const float* bhh1 = (const float*)d_in[15];
    const float* Wih2 = (const float*)d_in[16];
    const float* Whh2 = (const float*)d_in[17];
    const float* bih2 = (const float*)d_in[18];
    const float* bhh2 = (const float*)d_in[19];
    const float* cnfW = (const float*)d_in[20];
    const float* cnfb = (const float*)d_in[21];
    float* out = (float*)d_out;

    char* p = (char*)d_ws;
    auto alloc = [&](size_t bytes) -> void* {
        void* r = (void*)p;
        p += (bytes + 255) & ~(size_t)255;
        return r;
    };
    u16*   emb_p = (u16*)alloc((size_t)33280 * 416 * 2);
    u16*   x0    = (u16*)alloc((size_t)1152 * 416 * 2);
    u16*   ys0s  = (u16*)alloc((size_t)1136 * 1152 * 2);
    u16*   ys1s  = (u16*)alloc((size_t)1136 * 1152 * 2);
    u16*   ys2s  = (u16*)alloc((size_t)1184 * 416 * 2);   // +pad for gemm overread
    float* xW    = (float*)alloc((size_t)1120 * 4608 * 4);
    u16*   Wih0p = (u16*)alloc((size_t)4608 * 416 * 2);
    u16*   Whh0p = (u16*)alloc((size_t)4608 * 1152 * 2);
    u16*   Wih1p = (u16*)alloc((size_t)4608 * 1152 * 2);
    u16*   Whh1p = (u16*)alloc((size_t)4608 * 1152 * 2);
    u16*   Wih2p = (u16*)alloc((size_t)1664 * 1152 * 2);
    u16*   Whh2p = (u16*)alloc((size_t)1664 * 416 * 2);
    float* bias0 = (float*)alloc((size_t)4608 * 4);
    float* bias1 = (float*)alloc((size_t)4608 * 4);
    float* bias2 = (float*)alloc((size_t)1664 * 4);
    u16*   Wxp   = (u16*)alloc((size_t)416 * 416 * 2);
    float* wtv   = (float*)alloc((size_t)400 * 4);
    float* dwx   = (float*)alloc((size_t)400 * 4);
    float* dl    = (float*)alloc((size_t)NTOK * 4);
    float* e2    = (float*)alloc((size_t)NTOK * 4);
    float* uvec  = (float*)alloc((size_t)NTOK * 4);
    int*   bar   = (int*)alloc(4096);

    size_t OM = (size_t)SEQL * 16 * NTOK;
    float* oh1 = out + OM;
    float* oc1 = oh1 + 16 * 1150;
    float* oh2 = oc1 + 16 * 1150;
    float* oc2 = oh2 + 16 * 1150;
    float* oh3 = oc2 + 16 * 1150;
    float* oc3 = oh3 + 16 * 400;

    hipMemsetAsync(bar, 0, 4096, stream);
    hipMemsetAsync(ys0s, 0, (size_t)1136 * 1152 * 2, stream);
    hipMemsetAsync(ys1s, 0, (size_t)1136 * 1152 * 2, stream);
    hipMemsetAsync(ys2s, 0, (size_t)1184 * 416 * 2, stream);

    cvt_pad_k<<<2048, 256, 0, stream>>>(Wih0, Wih0p, 4, 1150, 1152, 400, 416, 400, 0);
    cvt_pad_k<<<2048, 256, 0, stream>>>(Whh0, Whh0p, 4, 1150, 1152, 1150, 1152, 1150, 0);
    cvt_pad_k<<<2048, 256, 0, stream>>>(Wih1, Wih1p, 4, 1150, 1152, 1150, 1152, 1150, 0);
    cvt_pad_k<<<2048, 256, 0, stream>>>(Whh1, Whh1p, 4, 1150, 1152, 1150, 1152, 1150, 0);
    cvt_pad_k<<<2048, 256, 0, stream>>>(Wih2, Wih2p, 4, 400, 416, 1150, 1152, 1150, 0);
    cvt_pad_k<<<2048, 256, 0, stream>>>(Whh2, Whh2p, 4, 400, 416, 400, 416, 400, 0);
    cvt_pad_k<<<2048, 256, 0, stream>>>(embW, emb_p, 1, 33278, 33280, 400, 416, 400, 0);
    cvt_pad_k<<<2048, 256, 0, stream>>>(cnfW, Wxp, 1, 400, 416, 400, 416, 401, 1);
    bias_k<<<(4 * 1152 + 255) / 256, 256, 0, stream>>>(bih0, bhh0, bias0, 1150, 1152);
    bias_k<<<(4 * 1152 + 255) / 256, 256, 0, stream>>>(bih1, bhh1, bias1, 1150, 1152);
    bias_k<<<(4 * 416 + 255) / 256, 256, 0, stream>>>(bih2, bhh2, bias2, 400, 416);
    wtdwx_k<<<2, 256, 0, stream>>>(cnfW, wtv, dwx);
    rowsumsq_k<<<NTOK, 64, 0, stream>>>(embW, e2, 400);

    // h0 -> ys slot 0
    h0cvt_k<<<(16 * 1152 + 255) / 256, 256, 0, stream>>>(h00, ys0s, 1150, 1152);
    h0cvt_k<<<(16 * 1152 + 255) / 256, 256, 0, stream>>>(h01, ys1s, 1150, 1152);
    h0cvt_k<<<(16 * 416 + 255) / 256, 256, 0, stream>>>(h02, ys2s, 400, 416);

    // CNF (independent): 64 rows/block, 1024 threads
    cnf_k<<<520, 1024, 0, stream>>>(embW, Wxp, wtv, cnfb, dwx, dl);
    ucomb_k<<<(NTOK + 255) / 256, 256, 0, stream>>>(e2, dl, uvec);

    // embedding + xW0 = x0 @ Wih0^T + (bih0+bhh0)
    embed_k<<<(1152 * 416 + 255) / 256, 256, 0, stream>>>(tokens, embW, x0);
    gemm_bt_k<<<dim3(72, 18), 256, 0, stream>>>(x0, Wih0p, xW, 416, 416, 416, 4608,
                                                1120, 4608, bias0);

    // persistent-weight LSTM (3 decoupled role pipelines, flat barriers)
    lstm_k<<<NBLK, 768, 0, stream>>>(
        c00, c01, c02, Whh0p, Wih1p, Whh1p, Wih2p, Whh2p,
        xW, bias2, bias1, ys0s, ys1s, ys2s,
        oh1, oc1, oh2, oc2, oh3, oc3, bar);

    // logits into d_out, then in-place log-softmax
    gemm_bt_k<<<dim3(520, 18), 256, 0, stream>>>(ys2s + (size_t)16 * 416, emb_p, out,
                                                 416, 416, 416, NTOK, 1120, NTOK, uvec);
    logsoftmax_k<<<1120, 256, 0, stream>>>(out, NTOK);
}